// Round 10
// baseline (260.413 us; speedup 1.0000x reference)
//
#include <hip/hip_runtime.h>
#include <math.h>

#define Bc 64
#define Nc 4
#define Ac 1024
#define Oc 128
#define Dc 256
#define Qc 256
#define Hc 128
#define BN (Bc*Nc)

using f4     = __attribute__((ext_vector_type(4))) float;
using f32x4  = __attribute__((ext_vector_type(4))) float;
using short8 = __attribute__((ext_vector_type(8))) short;
using us4    = __attribute__((ext_vector_type(4))) unsigned short;

__device__ inline float decode_t(const void* p) {
    int i = *(const int*)p;
    if (i >= 1 && i <= 1000000) return (float)i;
    return __int_as_float(i);
}

// round-to-nearest-even fp32 -> bf16
__device__ inline unsigned short bf16_rne(float x) {
    unsigned u = __builtin_bit_cast(unsigned, x);
    u += 0x7FFFu + ((u >> 16) & 1u);
    return (unsigned short)(u >> 16);
}

// split fp32 -> truncated bf16 hi + bf16(residual) lo.  x ~= hi + lo
__device__ inline void split_bf16(float x, unsigned short& hi, unsigned short& lo) {
    unsigned u = __builtin_bit_cast(unsigned, x);
    hi = (unsigned short)(u >> 16);
    float hif = __builtin_bit_cast(float, u & 0xFFFF0000u);
    float lof = x - hif;
    lo = (unsigned short)(__builtin_bit_cast(unsigned, lof) >> 16);
}

// VALU-only lane reduce within 16-lane rows via DPP row_ror (no LDS pipe).
template<int CTRL>
__device__ inline float dpp_ror_add(float x) {
    int yi = __builtin_amdgcn_update_dpp(0, __builtin_bit_cast(int, x),
                                         CTRL, 0xf, 0xf, true);
    return x + __builtin_bit_cast(float, yi);
}
__device__ inline float row16_sum(float v) {
    v = dpp_ror_add<0x128>(v);   // row_ror:8
    v = dpp_ror_add<0x124>(v);   // row_ror:4
    v = dpp_ror_add<0x122>(v);   // row_ror:2
    v = dpp_ror_add<0x121>(v);   // row_ror:1
    return v;
}

__device__ inline short8 pack_hi(const f4& a, const f4& b, short8& lo_out) {
    short8 hi;
    unsigned short h16, l16;
    #pragma unroll
    for (int j = 0; j < 4; j++) {
        split_bf16(a[j], h16, l16); hi[j] = (short)h16; lo_out[j] = (short)l16;
    }
    #pragma unroll
    for (int j = 0; j < 4; j++) {
        split_bf16(b[j], h16, l16); hi[4+j] = (short)h16; lo_out[4+j] = (short)l16;
    }
    return hi;
}

// ---------------------------------------------------------------------------
// prep_fused (verified R7/R9): ONE prep launch, no staging workspace.
//   blocks 0..511  : Mt[b][h][o] = sum_d W1[d][h]*obj[b][o][d] via MFMA;
//                    fragments from DIRECT fp32 loads + in-register hi/lo split.
//   blocks 512..767: qb[bn,h] = q[bn,:] @ W1q + b1[h].
// ---------------------------------------------------------------------------
__global__ __launch_bounds__(256, 2) void prep_fused_kernel(
    const float* __restrict__ obj, const float* __restrict__ W1,
    const float* __restrict__ q,   const float* __restrict__ b1,
    unsigned short* __restrict__ Mt_hi, unsigned short* __restrict__ Mt_lo,
    float* __restrict__ qb)
{
    __shared__ float qs[256];
    __shared__ float red[2][128];

    const int bid = blockIdx.x;
    const int t   = threadIdx.x;

    if (bid < 512) {
        // ---- M2 branch: 64h x 32o tile ----
        const int b    = bid >> 3;
        const int rr   = bid & 7;
        const int h0   = (rr & 1) * 64;
        const int o0   = (rr >> 1) * 32;
        const int wave = t >> 6, lane = t & 63;
        const int l15  = lane & 15, quad = lane >> 4;
        const int hh   = h0 + wave * 16 + l15;    // this lane's A row (h)

        short8 Ah[8], Al[8];
        #pragma unroll
        for (int ks = 0; ks < 8; ks++) {
            const int ko = ks * 32 + quad * 8;
            #pragma unroll
            for (int j = 0; j < 8; j++) {
                unsigned short h16, l16;
                split_bf16(W1[(size_t)(ko + j) * Hc + hh], h16, l16);
                Ah[ks][j] = (short)h16; Al[ks][j] = (short)l16;
            }
        }

        const float* ob0 = obj + ((size_t)b * Oc + o0 + l15) * Dc;
        const float* ob1 = obj + ((size_t)b * Oc + o0 + 16 + l15) * Dc;

        f32x4 acc0 = (f32x4)(0.f), acc1 = (f32x4)(0.f);
        #pragma unroll
        for (int ks = 0; ks < 8; ks++) {
            const int ko = ks * 32 + quad * 8;
            short8 B0l, B1l;
            short8 B0h = pack_hi(*(const f4*)(ob0 + ko), *(const f4*)(ob0 + ko + 4), B0l);
            short8 B1h = pack_hi(*(const f4*)(ob1 + ko), *(const f4*)(ob1 + ko + 4), B1l);
            acc0 = __builtin_amdgcn_mfma_f32_16x16x32_bf16(Al[ks], B0l, acc0, 0, 0, 0);
            acc0 = __builtin_amdgcn_mfma_f32_16x16x32_bf16(Al[ks], B0h, acc0, 0, 0, 0);
            acc0 = __builtin_amdgcn_mfma_f32_16x16x32_bf16(Ah[ks], B0l, acc0, 0, 0, 0);
            acc0 = __builtin_amdgcn_mfma_f32_16x16x32_bf16(Ah[ks], B0h, acc0, 0, 0, 0);
            acc1 = __builtin_amdgcn_mfma_f32_16x16x32_bf16(Al[ks], B1l, acc1, 0, 0, 0);
            acc1 = __builtin_amdgcn_mfma_f32_16x16x32_bf16(Al[ks], B1h, acc1, 0, 0, 0);
            acc1 = __builtin_amdgcn_mfma_f32_16x16x32_bf16(Ah[ks], B1l, acc1, 0, 0, 0);
            acc1 = __builtin_amdgcn_mfma_f32_16x16x32_bf16(Ah[ks], B1h, acc1, 0, 0, 0);
        }

        // C/D layout: col = l15 (o), row = quad*4 + r (h)
        #pragma unroll
        for (int r = 0; r < 4; r++) {
            int hrow = h0 + wave * 16 + quad * 4 + r;
            size_t base = ((size_t)b * Hc + hrow) * Oc + o0 + l15;
            unsigned short hh16, ll16;
            split_bf16(acc0[r], hh16, ll16);
            Mt_hi[base] = hh16; Mt_lo[base] = ll16;
            split_bf16(acc1[r], hh16, ll16);
            Mt_hi[base + 16] = hh16; Mt_lo[base + 16] = ll16;
        }
    } else {
        // ---- qb branch ----
        const int bn = bid - 512;
        qs[t] = q[bn * Qc + t];
        __syncthreads();

        const int h = t & 127, kq = t >> 7;   // kq = 0..1, 128 d each
        float acc = 0.f;
        const float* w = W1 + (size_t)(Dc + kq * 128) * Hc + h;
        #pragma unroll 8
        for (int d = 0; d < 128; ++d)
            acc += qs[kq * 128 + d] * w[(size_t)d * Hc];
        red[kq][h] = acc;
        __syncthreads();

        if (t < 128)
            qb[bn * Hc + t] = b1[t] + red[0][t] + red[1][t];
    }
}

// ---------------------------------------------------------------------------
// main_half: grid (512) = 2 blocks per bn, 512 thr, 2 blocks/CU.
// R10: software-pipeline depth 2 — three register tile-sets:
//   sv = current tile (feeds MFMA-staged LDS copy from last iter + phase-3)
//   nv = next tile, fully landed, staged to LDS during the exp-overlap
//   fv = tile+2, issued at tile start, in flight a FULL tile (~3-4k cyc >> 900)
// so no staging wave ever waits on an HBM miss at barrier2.
// ---------------------------------------------------------------------------
__global__ __launch_bounds__(512, 4) void main_half_kernel(
    const float* __restrict__ att1, const int* __restrict__ tags,
    const unsigned short* __restrict__ Mt_hi, const unsigned short* __restrict__ Mt_lo,
    const float* __restrict__ qb, const float* __restrict__ W2,
    const float* __restrict__ b2, const void* __restrict__ tptr,
    float* __restrict__ out_part, float* __restrict__ z_part)
{
    __shared__ unsigned short A_s[2][64][136]; // ping-pong bf16 tiles, 34.8 KB
    __shared__ float part2[64][9];             // logit partials, +1 pad
    __shared__ float part3[16][132];           // end-of-kernel o-reduce, 8.4 KB
    __shared__ float e_s[64];
    __shared__ float qb_s[128], w2_s[128];

    const int t    = threadIdx.x;
    const int lane = t & 63;
    const int wave = t >> 6;          // 0..7
    const int l15  = lane & 15;
    const int quad = lane >> 4;
    const int blk  = blockIdx.x;      // 0..511
    const int bn   = blk >> 1;
    const int half = blk & 1;
    const int b    = bn >> 2;
    const int hw   = wave * 16;       // h-group base
    const int g3   = t >> 5;          // owned row group 0..15
    const int o4   = (t & 31) * 4;    // owned o base (4 consecutive o)

    const float* att_half = att1 + ((size_t)bn * Ac + half * 512) * Oc;
    const int*   tg_base  = tags + (size_t)bn * Ac + half * 512;

    // ---- prologue: tile-0 loads ----
    f4 sv[4];
    #pragma unroll
    for (int s = 0; s < 4; s++) {
        int idx = t + 512 * s;
        sv[s] = *(const f4*)(att_half + (size_t)idx * 4);
    }

    // ---- B fragments (hi/lo), once per block ----
    const size_t brow = ((size_t)b * Hc + hw + l15) * Oc;
    short8 Bh[4], Bl[4];
    #pragma unroll
    for (int ks = 0; ks < 4; ks++) {
        const int ko = ks * 32 + quad * 8;
        Bh[ks] = *(const short8*)(Mt_hi + brow + ko);
        Bl[ks] = *(const short8*)(Mt_lo + brow + ko);
    }

    if (t < 128) { qb_s[t] = qb[bn * Hc + t]; w2_s[t] = W2[t]; }
    int tg_cur  = (t < 64) ? tg_base[t] : 0;
    const float b2v  = b2[0];
    const float tval = decode_t(tptr);

    // ---- prologue: stage tile 0 into A_s[0]; issue tile-1 loads ----
    #pragma unroll
    for (int s = 0; s < 4; s++) {
        int idx = t + 512 * s;
        int r = idx >> 5, c4 = idx & 31;
        us4 h4;
        #pragma unroll
        for (int j = 0; j < 4; j++) h4[j] = bf16_rne(sv[s][j]);
        *(us4*)&A_s[0][r][c4 * 4] = h4;
    }
    f4 nv[4];
    #pragma unroll
    for (int s = 0; s < 4; s++) {
        int idx = t + 512 * s;
        nv[s] = *(const f4*)(att_half + (size_t)(64 * Oc) + (size_t)idx * 4);
    }
    int tg_next = (t < 64) ? tg_base[64 + t] : 0;
    __syncthreads();

    float z_reg = 0.f;
    f4 out4 = {0.f, 0.f, 0.f, 0.f};   // this thread's out[o4..o4+3] partial

    #pragma unroll
    for (int tile = 0; tile < 8; ++tile) {
        const int buf = tile & 1;

        // ---- issue tile+2 loads (full-tile in-flight window) ----
        f4 fv[4];
        int tg_far = 0;
        if (tile < 6) {
            const float* fp = att_half + (size_t)(tile + 2) * 64 * Oc;
            #pragma unroll
            for (int s = 0; s < 4; s++) {
                int idx = t + 512 * s;
                fv[s] = *(const f4*)(fp + (size_t)idx * 4);
            }
            if (t < 64) tg_far = tg_base[(tile + 2) * 64 + t];
        }

        // ---- MFMA: A_rne * (Bhi + Blo) from A_s[buf] ----
        f32x4 acc[4];
        #pragma unroll
        for (int i = 0; i < 4; i++) acc[i] = (f32x4)(0.f);
        #pragma unroll
        for (int ks = 0; ks < 4; ks++) {
            const int ko = ks * 32 + quad * 8;
            #pragma unroll
            for (int i = 0; i < 4; i++) {
                short8 ah = *(const short8*)&A_s[buf][i * 16 + l15][ko];
                acc[i] = __builtin_amdgcn_mfma_f32_16x16x32_bf16(ah, Bh[ks], acc[i], 0, 0, 0);
                acc[i] = __builtin_amdgcn_mfma_f32_16x16x32_bf16(ah, Bl[ks], acc[i], 0, 0, 0);
            }
        }

        // ---- epilogue: +qb, relu, *W2; DPP row-reduce over the 16 h lanes ----
        // C/D layout: col(h) = l15, row(a) = i*16 + quad*4 + r
        {
            const float qbv = qb_s[hw + l15], w2v = w2_s[hw + l15];
            #pragma unroll
            for (int i = 0; i < 4; i++)
                #pragma unroll
                for (int r = 0; r < 4; r++) {
                    float v = acc[i][r] + qbv;
                    v = v > 0.f ? v : 0.f;
                    float s = row16_sum(v * w2v);   // VALU DPP, no LDS
                    if (l15 == 0)
                        part2[i * 16 + quad * 4 + r][wave] = s;
                }
        }
        __syncthreads();   // barrier1: part2 ready; A_s[buf] readers done

        // ---- exp (wave 0) OVERLAPPED with staging nv -> A_s[buf^1] ----
        if (t < 64) {
            float sum = b2v;
            #pragma unroll
            for (int x = 0; x < 8; x++) sum += part2[t][x];
            float logit = sum / tval;
            float e = (tg_cur > 0) ? __expf(logit) : 0.f;
            e_s[t] = e;
            z_reg += e;
        }
        if (tile < 7) {
            #pragma unroll
            for (int s = 0; s < 4; s++) {
                int idx = t + 512 * s;
                int r = idx >> 5, c4 = idx & 31;
                us4 h4;
                #pragma unroll
                for (int j = 0; j < 4; j++) h4[j] = bf16_rne(nv[s][j]);
                *(us4*)&A_s[buf ^ 1][r][c4 * 4] = h4;
            }
        }
        __syncthreads();   // barrier2: e_s ready; A_s[buf^1] staged

        // ---- phase 3: out4 += e[row]*sv — registers, zero tile LDS ----
        #pragma unroll
        for (int s = 0; s < 4; s++) {
            const float ev = e_s[g3 + 16 * s];
            out4[0] += ev * sv[s][0];
            out4[1] += ev * sv[s][1];
            out4[2] += ev * sv[s][2];
            out4[3] += ev * sv[s][3];
        }

        // ---- rotate the pipeline ----
        if (tile < 7) {
            #pragma unroll
            for (int s = 0; s < 4; s++) sv[s] = nv[s];
            tg_cur = tg_next;
            if (tile < 6) {
                #pragma unroll
                for (int s = 0; s < 4; s++) nv[s] = fv[s];
                tg_next = tg_far;
            }
        }
    }

    // ---- finalize: one part3 write + reduce, z reduce, store ----
    __syncthreads();
    *(f4*)&part3[g3][o4] = out4;
    __syncthreads();
    if (t < 128) {
        float s = 0.f;
        #pragma unroll
        for (int g = 0; g < 16; g++) s += part3[g][t];
        out_part[(size_t)blk * 128 + t] = s;
    }
    if (t < 64) {   // all z_reg live in wave 0
        float z = z_reg;
        #pragma unroll
        for (int off = 32; off > 0; off >>= 1) z += __shfl_down(z, off);
        if (t == 0) z_part[blk] = z;
    }
}

// ---------------------------------------------------------------------------
// finalize: out[bn,o] = (P0+P1)/(Z0+Z1)
// ---------------------------------------------------------------------------
__global__ __launch_bounds__(128) void finalize_kernel(
    const float* __restrict__ out_part, const float* __restrict__ z_part,
    float* __restrict__ out)
{
    const int bn = blockIdx.x;
    const int t  = threadIdx.x;
    const float Z = z_part[bn * 2] + z_part[bn * 2 + 1];
    const float v = out_part[(size_t)(bn * 2) * 128 + t]
                  + out_part[(size_t)(bn * 2 + 1) * 128 + t];
    out[(size_t)bn * 128 + t] = v / Z;
}

extern "C" void kernel_launch(void* const* d_in, const int* in_sizes, int n_in,
                              void* d_out, int out_size, void* d_ws, size_t ws_size,
                              hipStream_t stream)
{
    (void)in_sizes; (void)n_in; (void)out_size; (void)ws_size;

    const float* q    = (const float*)d_in[0];
    const float* att1 = (const float*)d_in[1];
    const float* obj  = (const float*)d_in[2];
    const int*   tags = (const int*)d_in[3];
    const float* W1   = (const float*)d_in[4];
    const float* b1   = (const float*)d_in[5];
    const float* W2   = (const float*)d_in[6];
    const float* b2   = (const float*)d_in[7];
    const void*  tptr = (const void*)d_in[8];
    float* out = (float*)d_out;

    char* wsb = (char*)d_ws;
    unsigned short* Mt_hi = (unsigned short*)wsb;                          // 2 MB
    unsigned short* Mt_lo = (unsigned short*)(wsb + (size_t)2*1024*1024);  // 2 MB
    float* qbuf     = (float*)(wsb + (size_t)4*1024*1024);  // 128 KB
    float* out_part = (float*)(wsb + (size_t)5*1024*1024);  // 256 KB
    float* z_part   = (float*)(wsb + (size_t)6*1024*1024);  // 2 KB

    prep_fused_kernel<<<dim3(512 + BN), 256, 0, stream>>>(obj, W1, q, b1,
                                                          Mt_hi, Mt_lo, qbuf);
    main_half_kernel<<<dim3(2 * BN), 512, 0, stream>>>(att1, tags, Mt_hi, Mt_lo,
                                                       qbuf, W2, b2, tptr,
                                                       out_part, z_part);
    finalize_kernel<<<dim3(BN), 128, 0, stream>>>(out_part, z_part, out);
}

// Round 11
// 228.507 us; speedup vs baseline: 1.1396x; 1.1396x over previous
//
#include <hip/hip_runtime.h>
#include <math.h>

#define Bc 64
#define Nc 4
#define Ac 1024
#define Oc 128
#define Dc 256
#define Qc 256
#define Hc 128
#define BN (Bc*Nc)

using f4     = __attribute__((ext_vector_type(4))) float;
using f32x4  = __attribute__((ext_vector_type(4))) float;
using short8 = __attribute__((ext_vector_type(8))) short;
using us4    = __attribute__((ext_vector_type(4))) unsigned short;

__device__ inline float decode_t(const void* p) {
    int i = *(const int*)p;
    if (i >= 1 && i <= 1000000) return (float)i;
    return __int_as_float(i);
}

// round-to-nearest-even fp32 -> bf16
__device__ inline unsigned short bf16_rne(float x) {
    unsigned u = __builtin_bit_cast(unsigned, x);
    u += 0x7FFFu + ((u >> 16) & 1u);
    return (unsigned short)(u >> 16);
}

// split fp32 -> truncated bf16 hi + bf16(residual) lo.  x ~= hi + lo
__device__ inline void split_bf16(float x, unsigned short& hi, unsigned short& lo) {
    unsigned u = __builtin_bit_cast(unsigned, x);
    hi = (unsigned short)(u >> 16);
    float hif = __builtin_bit_cast(float, u & 0xFFFF0000u);
    float lof = x - hif;
    lo = (unsigned short)(__builtin_bit_cast(unsigned, lof) >> 16);
}

// VALU-only lane reduce within 16-lane rows via DPP row_ror (no LDS pipe).
template<int CTRL>
__device__ inline float dpp_ror_add(float x) {
    int yi = __builtin_amdgcn_update_dpp(0, __builtin_bit_cast(int, x),
                                         CTRL, 0xf, 0xf, true);
    return x + __builtin_bit_cast(float, yi);
}
__device__ inline float row16_sum(float v) {
    v = dpp_ror_add<0x128>(v);   // row_ror:8
    v = dpp_ror_add<0x124>(v);   // row_ror:4
    v = dpp_ror_add<0x122>(v);   // row_ror:2
    v = dpp_ror_add<0x121>(v);   // row_ror:1
    return v;
}

__device__ inline short8 pack_hi(const f4& a, const f4& b, short8& lo_out) {
    short8 hi;
    unsigned short h16, l16;
    #pragma unroll
    for (int j = 0; j < 4; j++) {
        split_bf16(a[j], h16, l16); hi[j] = (short)h16; lo_out[j] = (short)l16;
    }
    #pragma unroll
    for (int j = 0; j < 4; j++) {
        split_bf16(b[j], h16, l16); hi[4+j] = (short)h16; lo_out[4+j] = (short)l16;
    }
    return hi;
}

// ---------------------------------------------------------------------------
// prep_fused (verified R7/R9): ONE prep launch, no staging workspace.
//   blocks 0..511  : Mt[b][h][o] = sum_d W1[d][h]*obj[b][o][d] via MFMA;
//                    A (W1T) and B (obj) fragments from DIRECT fp32 loads
//                    + in-register hi/lo split.
//   blocks 512..767: qb[bn,h] = q[bn,:] @ W1q + b1[h].
// ---------------------------------------------------------------------------
__global__ __launch_bounds__(256, 2) void prep_fused_kernel(
    const float* __restrict__ obj, const float* __restrict__ W1,
    const float* __restrict__ q,   const float* __restrict__ b1,
    unsigned short* __restrict__ Mt_hi, unsigned short* __restrict__ Mt_lo,
    float* __restrict__ qb)
{
    __shared__ float qs[256];
    __shared__ float red[2][128];

    const int bid = blockIdx.x;
    const int t   = threadIdx.x;

    if (bid < 512) {
        // ---- M2 branch: 64h x 32o tile ----
        const int b    = bid >> 3;
        const int rr   = bid & 7;
        const int h0   = (rr & 1) * 64;
        const int o0   = (rr >> 1) * 32;
        const int wave = t >> 6, lane = t & 63;
        const int l15  = lane & 15, quad = lane >> 4;
        const int hh   = h0 + wave * 16 + l15;    // this lane's A row (h)

        short8 Ah[8], Al[8];
        #pragma unroll
        for (int ks = 0; ks < 8; ks++) {
            const int ko = ks * 32 + quad * 8;
            #pragma unroll
            for (int j = 0; j < 8; j++) {
                unsigned short h16, l16;
                split_bf16(W1[(size_t)(ko + j) * Hc + hh], h16, l16);
                Ah[ks][j] = (short)h16; Al[ks][j] = (short)l16;
            }
        }

        const float* ob0 = obj + ((size_t)b * Oc + o0 + l15) * Dc;
        const float* ob1 = obj + ((size_t)b * Oc + o0 + 16 + l15) * Dc;

        f32x4 acc0 = (f32x4)(0.f), acc1 = (f32x4)(0.f);
        #pragma unroll
        for (int ks = 0; ks < 8; ks++) {
            const int ko = ks * 32 + quad * 8;
            short8 B0l, B1l;
            short8 B0h = pack_hi(*(const f4*)(ob0 + ko), *(const f4*)(ob0 + ko + 4), B0l);
            short8 B1h = pack_hi(*(const f4*)(ob1 + ko), *(const f4*)(ob1 + ko + 4), B1l);
            acc0 = __builtin_amdgcn_mfma_f32_16x16x32_bf16(Al[ks], B0l, acc0, 0, 0, 0);
            acc0 = __builtin_amdgcn_mfma_f32_16x16x32_bf16(Al[ks], B0h, acc0, 0, 0, 0);
            acc0 = __builtin_amdgcn_mfma_f32_16x16x32_bf16(Ah[ks], B0l, acc0, 0, 0, 0);
            acc0 = __builtin_amdgcn_mfma_f32_16x16x32_bf16(Ah[ks], B0h, acc0, 0, 0, 0);
            acc1 = __builtin_amdgcn_mfma_f32_16x16x32_bf16(Al[ks], B1l, acc1, 0, 0, 0);
            acc1 = __builtin_amdgcn_mfma_f32_16x16x32_bf16(Al[ks], B1h, acc1, 0, 0, 0);
            acc1 = __builtin_amdgcn_mfma_f32_16x16x32_bf16(Ah[ks], B1l, acc1, 0, 0, 0);
            acc1 = __builtin_amdgcn_mfma_f32_16x16x32_bf16(Ah[ks], B1h, acc1, 0, 0, 0);
        }

        // C/D layout: col = l15 (o), row = quad*4 + r (h)
        #pragma unroll
        for (int r = 0; r < 4; r++) {
            int hrow = h0 + wave * 16 + quad * 4 + r;
            size_t base = ((size_t)b * Hc + hrow) * Oc + o0 + l15;
            unsigned short hh16, ll16;
            split_bf16(acc0[r], hh16, ll16);
            Mt_hi[base] = hh16; Mt_lo[base] = ll16;
            split_bf16(acc1[r], hh16, ll16);
            Mt_hi[base + 16] = hh16; Mt_lo[base + 16] = ll16;
        }
    } else {
        // ---- qb branch ----
        const int bn = bid - 512;
        qs[t] = q[bn * Qc + t];
        __syncthreads();

        const int h = t & 127, kq = t >> 7;   // kq = 0..1, 128 d each
        float acc = 0.f;
        const float* w = W1 + (size_t)(Dc + kq * 128) * Hc + h;
        #pragma unroll 8
        for (int d = 0; d < 128; ++d)
            acc += qs[kq * 128 + d] * w[(size_t)d * Hc];
        red[kq][h] = acc;
        __syncthreads();

        if (t < 128)
            qb[bn * Hc + t] = b1[t] + red[0][t] + red[1][t];
    }
}

// ---------------------------------------------------------------------------
// main_half (R8/R9 structure, verified best): grid (512) = 2 blocks per bn,
// 512 thr, 2 blocks/CU. Ping-pong A_s, 2 barriers/tile, exp overlapped with
// staging, register-resident phase-3, depth-1 prefetch (R10 lesson: depth-2
// + unrolled tile loop -> scratch spills, 96 MB spill writes, +31 us).
// NO fence/atomic finalize (R7 lesson: device-scope fences serialize L2).
// ---------------------------------------------------------------------------
__global__ __launch_bounds__(512, 4) void main_half_kernel(
    const float* __restrict__ att1, const int* __restrict__ tags,
    const unsigned short* __restrict__ Mt_hi, const unsigned short* __restrict__ Mt_lo,
    const float* __restrict__ qb, const float* __restrict__ W2,
    const float* __restrict__ b2, const void* __restrict__ tptr,
    float* __restrict__ out_part, float* __restrict__ z_part)
{
    __shared__ unsigned short A_s[2][64][136]; // ping-pong bf16 tiles, 34.8 KB
    __shared__ float part2[64][9];             // logit partials, +1 pad
    __shared__ float part3[16][132];           // end-of-kernel o-reduce, 8.4 KB
    __shared__ float e_s[64];
    __shared__ float qb_s[128], w2_s[128];

    const int t    = threadIdx.x;
    const int lane = t & 63;
    const int wave = t >> 6;          // 0..7
    const int l15  = lane & 15;
    const int quad = lane >> 4;
    const int blk  = blockIdx.x;      // 0..511
    const int bn   = blk >> 1;
    const int half = blk & 1;
    const int b    = bn >> 2;
    const int hw   = wave * 16;       // h-group base
    const int g3   = t >> 5;          // owned row group 0..15
    const int o4   = (t & 31) * 4;    // owned o base (4 consecutive o)

    const float* att_half = att1 + ((size_t)bn * Ac + half * 512) * Oc;

    // ---- prologue: tile-0 staging loads (HBM) ----
    f4 sv[4];
    #pragma unroll
    for (int s = 0; s < 4; s++) {
        int idx = t + 512 * s;
        sv[s] = *(const f4*)(att_half + (size_t)idx * 4);
    }

    // ---- B fragments (hi/lo), once per block ----
    const size_t brow = ((size_t)b * Hc + hw + l15) * Oc;
    short8 Bh[4], Bl[4];
    #pragma unroll
    for (int ks = 0; ks < 4; ks++) {
        const int ko = ks * 32 + quad * 8;
        Bh[ks] = *(const short8*)(Mt_hi + brow + ko);
        Bl[ks] = *(const short8*)(Mt_lo + brow + ko);
    }

    if (t < 128) { qb_s[t] = qb[bn * Hc + t]; w2_s[t] = W2[t]; }
    int tg_cur = (t < 64) ? tags[(size_t)bn * Ac + half * 512 + t] : 0;
    const float b2v  = b2[0];
    const float tval = decode_t(tptr);

    // ---- prologue: stage tile 0 into A_s[0] ----
    #pragma unroll
    for (int s = 0; s < 4; s++) {
        int idx = t + 512 * s;
        int r = idx >> 5, c4 = idx & 31;
        us4 h4;
        #pragma unroll
        for (int j = 0; j < 4; j++) h4[j] = bf16_rne(sv[s][j]);
        *(us4*)&A_s[0][r][c4 * 4] = h4;
    }
    __syncthreads();

    float z_reg = 0.f;
    f4 out4 = {0.f, 0.f, 0.f, 0.f};   // this thread's out[o4..o4+3] partial

    for (int tile = 0; tile < 8; ++tile) {
        const int buf = tile & 1;

        // ---- issue next-tile loads first (latency hides under MFMA) ----
        f4 nv[4];
        int tg_next = 0;
        if (tile < 7) {
            const float* np = att_half + (size_t)(tile + 1) * 64 * Oc;
            #pragma unroll
            for (int s = 0; s < 4; s++) {
                int idx = t + 512 * s;
                nv[s] = *(const f4*)(np + (size_t)idx * 4);
            }
            if (t < 64) tg_next = tags[(size_t)bn * Ac + half * 512 + (tile + 1) * 64 + t];
        }

        // ---- MFMA: A_rne * (Bhi + Blo) from A_s[buf] ----
        f32x4 acc[4];
        #pragma unroll
        for (int i = 0; i < 4; i++) acc[i] = (f32x4)(0.f);
        #pragma unroll
        for (int ks = 0; ks < 4; ks++) {
            const int ko = ks * 32 + quad * 8;
            #pragma unroll
            for (int i = 0; i < 4; i++) {
                short8 ah = *(const short8*)&A_s[buf][i * 16 + l15][ko];
                acc[i] = __builtin_amdgcn_mfma_f32_16x16x32_bf16(ah, Bh[ks], acc[i], 0, 0, 0);
                acc[i] = __builtin_amdgcn_mfma_f32_16x16x32_bf16(ah, Bl[ks], acc[i], 0, 0, 0);
            }
        }

        // ---- epilogue: +qb, relu, *W2; DPP row-reduce over the 16 h lanes ----
        // C/D layout: col(h) = l15, row(a) = i*16 + quad*4 + r
        {
            const float qbv = qb_s[hw + l15], w2v = w2_s[hw + l15];
            #pragma unroll
            for (int i = 0; i < 4; i++)
                #pragma unroll
                for (int r = 0; r < 4; r++) {
                    float v = acc[i][r] + qbv;
                    v = v > 0.f ? v : 0.f;
                    float s = row16_sum(v * w2v);   // VALU DPP, no LDS
                    if (l15 == 0)
                        part2[i * 16 + quad * 4 + r][wave] = s;
                }
        }
        __syncthreads();   // barrier1: part2 ready; A_s[buf] readers done

        // ---- exp (wave 0) OVERLAPPED with staging tile+1 into A_s[buf^1] ----
        if (t < 64) {
            float sum = b2v;
            #pragma unroll
            for (int x = 0; x < 8; x++) sum += part2[t][x];
            float logit = sum / tval;
            float e = (tg_cur > 0) ? __expf(logit) : 0.f;
            e_s[t] = e;
            z_reg += e;
        }
        if (tile < 7) {
            #pragma unroll
            for (int s = 0; s < 4; s++) {
                int idx = t + 512 * s;
                int r = idx >> 5, c4 = idx & 31;
                us4 h4;
                #pragma unroll
                for (int j = 0; j < 4; j++) h4[j] = bf16_rne(nv[s][j]);
                *(us4*)&A_s[buf ^ 1][r][c4 * 4] = h4;
            }
        }
        __syncthreads();   // barrier2: e_s ready; A_s[buf^1] staged

        // ---- phase 3: out4 += e[row]*sv — registers, zero tile LDS ----
        #pragma unroll
        for (int s = 0; s < 4; s++) {
            const float ev = e_s[g3 + 16 * s];
            out4[0] += ev * sv[s][0];
            out4[1] += ev * sv[s][1];
            out4[2] += ev * sv[s][2];
            out4[3] += ev * sv[s][3];
        }

        // ---- rotate prefetched tile in ----
        if (tile < 7) {
            #pragma unroll
            for (int s = 0; s < 4; s++) sv[s] = nv[s];
            tg_cur = tg_next;
        }
    }

    // ---- finalize: one part3 write + reduce, z reduce, store ----
    __syncthreads();
    *(f4*)&part3[g3][o4] = out4;
    __syncthreads();
    if (t < 128) {
        float s = 0.f;
        #pragma unroll
        for (int g = 0; g < 16; g++) s += part3[g][t];
        out_part[(size_t)blk * 128 + t] = s;
    }
    if (t < 64) {   // all z_reg live in wave 0
        float z = z_reg;
        #pragma unroll
        for (int off = 32; off > 0; off >>= 1) z += __shfl_down(z, off);
        if (t == 0) z_part[blk] = z;
    }
}

// ---------------------------------------------------------------------------
// finalize: out[bn,o] = (P0+P1)/(Z0+Z1)
// ---------------------------------------------------------------------------
__global__ __launch_bounds__(128) void finalize_kernel(
    const float* __restrict__ out_part, const float* __restrict__ z_part,
    float* __restrict__ out)
{
    const int bn = blockIdx.x;
    const int t  = threadIdx.x;
    const float Z = z_part[bn * 2] + z_part[bn * 2 + 1];
    const float v = out_part[(size_t)(bn * 2) * 128 + t]
                  + out_part[(size_t)(bn * 2 + 1) * 128 + t];
    out[(size_t)bn * 128 + t] = v / Z;
}

extern "C" void kernel_launch(void* const* d_in, const int* in_sizes, int n_in,
                              void* d_out, int out_size, void* d_ws, size_t ws_size,
                              hipStream_t stream)
{
    (void)in_sizes; (void)n_in; (void)out_size; (void)ws_size;

    const float* q    = (const float*)d_in[0];
    const float* att1 = (const float*)d_in[1];
    const float* obj  = (const float*)d_in[2];
    const int*   tags = (const int*)d_in[3];
    const float* W1   = (const float*)d_in[4];
    const float* b1   = (const float*)d_in[5];
    const float* W2   = (const float*)d_in[6];
    const float* b2   = (const float*)d_in[7];
    const void*  tptr = (const void*)d_in[8];
    float* out = (float*)d_out;

    char* wsb = (char*)d_ws;
    unsigned short* Mt_hi = (unsigned short*)wsb;                          // 2 MB
    unsigned short* Mt_lo = (unsigned short*)(wsb + (size_t)2*1024*1024);  // 2 MB
    float* qbuf     = (float*)(wsb + (size_t)4*1024*1024);  // 128 KB
    float* out_part = (float*)(wsb + (size_t)5*1024*1024);  // 256 KB
    float* z_part   = (float*)(wsb + (size_t)6*1024*1024);  // 2 KB

    prep_fused_kernel<<<dim3(512 + BN), 256, 0, stream>>>(obj, W1, q, b1,
                                                          Mt_hi, Mt_lo, qbuf);
    main_half_kernel<<<dim3(2 * BN), 512, 0, stream>>>(att1, tags, Mt_hi, Mt_lo,
                                                       qbuf, W2, b2, tptr,
                                                       out_part, z_part);
    finalize_kernel<<<dim3(BN), 128, 0, stream>>>(out_part, z_part, out);
}